// Round 14
// baseline (245.522 us; speedup 1.0000x reference)
//
#include <hip/hip_runtime.h>

typedef _Float16 f16;
typedef _Float16 f16x8 __attribute__((ext_vector_type(8)));
typedef float f32x4 __attribute__((ext_vector_type(4)));
typedef int i32x4 __attribute__((ext_vector_type(4)));
typedef unsigned int u32;

#define NN 8192
#define FF 256
#define MASK_NEG -1.0e30f

// async global->LDS, 16B per lane. LDS dest = wave-uniform base + lane*16.
__device__ __forceinline__ void gload_lds16(const void* gsrc, void* ldst) {
    __builtin_amdgcn_global_load_lds(
        (const __attribute__((address_space(1))) u32*)gsrc,
        (__attribute__((address_space(3))) u32*)ldst, 16, 0, 0);
}

// ---------------- K0: W^T in f16 (so K1 B-frags are contiguous) -------------
__global__ void k0_wt(const float* __restrict__ w, f16* __restrict__ wt) {
    int n = blockIdx.x;
    int k = threadIdx.x;
    wt[n * FF + k] = (f16)w[k * FF + n];
}

// ---------------- K1: h = x @ W  (f16 out) ----------------------------------
__global__ __launch_bounds__(256) void k1_h(const float* __restrict__ x,
                                            const f16* __restrict__ wt,
                                            f16* __restrict__ h) {
    int tid = threadIdx.x;
    int wave = tid >> 6, lane = tid & 63, l15 = lane & 15, lg = lane >> 4;
    int rowBase = blockIdx.x * 32 + (wave & 1) * 16;
    int colBase = (wave >> 1) * 128;

    f16x8 afr[8];
    const float* xr = x + (size_t)(rowBase + l15) * FF + lg * 8;
#pragma unroll
    for (int kk = 0; kk < 8; ++kk) {
        float4 a0 = *(const float4*)(xr + kk * 32);
        float4 a1 = *(const float4*)(xr + kk * 32 + 4);
        f16x8 a;
        a[0] = (f16)a0.x; a[1] = (f16)a0.y; a[2] = (f16)a0.z; a[3] = (f16)a0.w;
        a[4] = (f16)a1.x; a[5] = (f16)a1.y; a[6] = (f16)a1.z; a[7] = (f16)a1.w;
        afr[kk] = a;
    }
#pragma unroll
    for (int cs = 0; cs < 8; ++cs) {
        int col = colBase + cs * 16 + l15;
        f32x4 acc = {0.f, 0.f, 0.f, 0.f};
        const f16* wr = wt + (size_t)col * FF + lg * 8;
#pragma unroll
        for (int kk = 0; kk < 8; ++kk) {
            f16x8 b = *(const f16x8*)(wr + kk * 32);
            acc = __builtin_amdgcn_mfma_f32_16x16x32_f16(afr[kk], b, acc, 0, 0, 0);
        }
#pragma unroll
        for (int r = 0; r < 4; ++r)
            h[(size_t)(rowBase + 4 * lg + r) * FF + col] = (f16)acc[r];
    }
}

// ---------------- K2a: fused adj-pack + partial row-max / row-sumexp --------
// grid 1024 = 128 row-blocks (64 rows) x 8 col-splits (1024 cols).
// 4 waves x 16 rows; 16 tiles of 64 cols; single 32 KB h-panel, 2 barriers
// per tile (replay-stable r11/r13 skeleton). Tiles processed in a per-block
// ROTATED order (online softmax / mask / out are tile-order-independent) so
// co-resident blocks' stage-drain windows interleave instead of convoying.
__global__ __launch_bounds__(256, 4) void k2a(const f16* __restrict__ h,
                                              const int* __restrict__ adj,
                                              u32* __restrict__ maskbits,
                                              float* __restrict__ pm,
                                              float* __restrict__ ps) {
    __shared__ __align__(16) char hbuf[32768];
    int tid = threadIdx.x;
    int wave = tid >> 6, lane = tid & 63, l15 = lane & 15, lg = lane >> 4;
    int bid = blockIdx.x;
    int rb = bid >> 3, split = bid & 7;
    int rowBase = rb * 64;
    int c0 = split * 1024;
    int ph4 = ((bid ^ (bid >> 8)) & 3) * 4;  // per-block tile-phase rotation

    // A-frags: 16 rows x K=256 (16x16x32 layout, validated r5/r6/r7)
    f16x8 A[8];
    {
        const f16* ap = h + (size_t)(rowBase + wave * 16 + l15) * FF + lg * 8;
#pragma unroll
        for (int kk = 0; kk < 8; ++kk) A[kk] = *(const f16x8*)(ap + kk * 32);
    }
    float m[4], s[4];
#pragma unroll
    for (int r = 0; r < 4; ++r) { m[r] = MASK_NEG; s[r] = 0.f; }

    // adj: lane covers row rowBase+wave*16+(lane>>2), col-quarter (lane&3)*16
    int prow = rowBase + wave * 16 + (lane >> 2);
    int q = lane & 3;
    const int* arow = adj + (size_t)prow * NN + c0 + q * 16;
    i32x4 aj[4];
    {
        const i32x4* p = (const i32x4*)(arow + ph4 * 64);
#pragma unroll
        for (int k = 0; k < 4; ++k) aj[k] = __builtin_nontemporal_load(p + k);
    }

#pragma unroll 1
    for (int t = 0; t < 16; ++t) {
        int TT = (t + ph4) & 15;        // tile processed this iteration
        int TN = (TT + 1) & 15;         // tile staged for next iteration
        __syncthreads();  // readers of previous panel done
        // stage h[c0+TT*64 .. +64) x 256 f16 -> LDS (pre-swizzled source).
        // LDS[c][slot] = h[c][slot ^ (c&31)] in 16B slots.  (r11 verbatim)
        {
            const char* hb = (const char*)h + (size_t)(c0 + TT * 64) * 512;
#pragma unroll
            for (int i = 0; i < 8; ++i) {
                int sb = i * 256 + wave * 64;   // wave-uniform slot base
                int c = i * 8 + wave * 2 + (lane >> 5);
                gload_lds16(hb + (size_t)c * 512 + (((lane & 31) ^ (c & 31)) << 4),
                            hbuf + (size_t)sb * 16);
            }
        }
        __syncthreads();  // vmcnt drain: panel (and last iter's aj) ready

        // pack this lane's 16 bits; merge halves so lanes 4*wr+2*w hold
        // the full word for (row wr, word w of tile TT)
        u32 wp = 0;
#pragma unroll
        for (int k = 0; k < 4; ++k)
#pragma unroll
            for (int c = 0; c < 4; ++c)
                wp |= (aj[k][c] > 0 ? 1u : 0u) << (k * 4 + c);
        wp <<= (q & 1) * 16;
        u32 word = wp | (u32)__shfl_xor((int)wp, 1, 64);
        if ((lane & 1) == 0)
            maskbits[(size_t)(split * 32 + TT * 2 + ((lane >> 1) & 1)) * NN
                     + prow] = word;

        // prefetch adj for tile TN (hidden under GEMM+softmax)
        if (t + 1 < 16) {
            const i32x4* p = (const i32x4*)(arow + TN * 64);
#pragma unroll
            for (int k = 0; k < 4; ++k) aj[k] = __builtin_nontemporal_load(p + k);
        }

        // GEMM: 16 rows x 64 cols (4 subtiles of 16), B from swizzled LDS
        f32x4 acc0 = {0.f, 0.f, 0.f, 0.f}, acc1 = {0.f, 0.f, 0.f, 0.f};
        f32x4 acc2 = {0.f, 0.f, 0.f, 0.f}, acc3 = {0.f, 0.f, 0.f, 0.f};
#pragma unroll
        for (int kk = 0; kk < 8; ++kk) {
            int ks = kk * 4 + lg;  // 16B k-slot within a col's 512B row
            f16x8 b0 = *(const f16x8*)(hbuf + (size_t)l15 * 512
                                       + ((ks ^ l15) << 4));
            f16x8 b1 = *(const f16x8*)(hbuf + (size_t)(16 + l15) * 512
                                       + ((ks ^ (16 + l15)) << 4));
            f16x8 b2 = *(const f16x8*)(hbuf + (size_t)(32 + l15) * 512
                                       + ((ks ^ l15) << 4));
            f16x8 b3 = *(const f16x8*)(hbuf + (size_t)(48 + l15) * 512
                                       + ((ks ^ (16 + l15)) << 4));
            acc0 = __builtin_amdgcn_mfma_f32_16x16x32_f16(A[kk], b0, acc0, 0, 0, 0);
            acc1 = __builtin_amdgcn_mfma_f32_16x16x32_f16(A[kk], b1, acc1, 0, 0, 0);
            acc2 = __builtin_amdgcn_mfma_f32_16x16x32_f16(A[kk], b2, acc2, 0, 0, 0);
            acc3 = __builtin_amdgcn_mfma_f32_16x16x32_f16(A[kk], b3, acc3, 0, 0, 0);
        }

        // online softmax, one rescale per (r, tile). Bogus accumulation while
        // m==-1e30 is killed by exp(-1e30 - real) = 0 at first unmasked value.
#pragma unroll
        for (int r = 0; r < 4; ++r) {
            int R = 4 * lg + r;  // C/D row = 4*(lane>>4)+reg (validated r5/r6)
            u32 wA = (u32)__shfl((int)word, 4 * R, 64);      // word 0: cols 0..31
            u32 wB = (u32)__shfl((int)word, 4 * R + 2, 64);  // word 1: cols 32..63
            float v0 = ((wA >> l15) & 1u) ? acc0[r] : MASK_NEG;
            float v1 = ((wA >> (16 + l15)) & 1u) ? acc1[r] : MASK_NEG;
            float v2 = ((wB >> l15) & 1u) ? acc2[r] : MASK_NEG;
            float v3 = ((wB >> (16 + l15)) & 1u) ? acc3[r] : MASK_NEG;
            float mn = fmaxf(m[r],
                             fmaxf(fmaxf(v0, v1), fmaxf(v2, v3)));
            s[r] = s[r] * __expf(m[r] - mn) + __expf(v0 - mn) + __expf(v1 - mn)
                 + __expf(v2 - mn) + __expf(v3 - mn);
            m[r] = mn;
        }
    }

    // reduce across the 16 l15-lanes (disjoint column sets per lane)
#pragma unroll
    for (int off = 1; off < 16; off <<= 1) {
#pragma unroll
        for (int r = 0; r < 4; ++r) {
            float om = __shfl_xor(m[r], off);
            float os = __shfl_xor(s[r], off);
            float mn = fmaxf(m[r], om);
            s[r] = s[r] * __expf(m[r] - mn) + os * __expf(om - mn);
            m[r] = mn;
        }
    }
    if (l15 == 0) {  // lanes 0,16,32,48 -> lg 0..3 -> rows 4*lg+r
#pragma unroll
        for (int r = 0; r < 4; ++r) {
            int row = rowBase + wave * 16 + 4 * lg + r;
            pm[(size_t)split * NN + row] = m[r];
            ps[(size_t)split * NN + row] = s[r];
        }
    }
}

// ---------------- K2r: reduce 8 partials -> C = M + ln(S) -------------------
__global__ void k2r(const float* __restrict__ pm, const float* __restrict__ ps,
                    float* __restrict__ cvec) {
    int row = blockIdx.x * 256 + threadIdx.x;
    float M = MASK_NEG, S = 0.f;
#pragma unroll
    for (int i = 0; i < 8; ++i) {
        float m = pm[(size_t)i * NN + row];
        float s = ps[(size_t)i * NN + row];
        float mn = fmaxf(M, m);
        S = S * __expf(M - mn) + s * __expf(m - mn);
        M = mn;
    }
    cvec[row] = M + __logf(S);  // out = exp(v - C)
}

// ---------------- K2b: recompute e, write softmax ---------------------------
// same geometry/sync skeleton as k2a (incl. tile rotation); writes out (NT)
__global__ __launch_bounds__(256, 4) void k2b(const f16* __restrict__ h,
                                              const u32* __restrict__ maskbits,
                                              const float* __restrict__ cvec,
                                              float* __restrict__ out) {
    __shared__ __align__(16) char hbuf[32768];
    int tid = threadIdx.x;
    int wave = tid >> 6, lane = tid & 63, l15 = lane & 15, lg = lane >> 4;
    int bid = blockIdx.x;
    int rb = bid >> 3, split = bid & 7;
    int rowBase = rb * 64;
    int c0 = split * 1024;
    int ph4 = ((bid ^ (bid >> 8)) & 3) * 4;

    f16x8 A[8];
    {
        const f16* ap = h + (size_t)(rowBase + wave * 16 + l15) * FF + lg * 8;
#pragma unroll
        for (int kk = 0; kk < 8; ++kk) A[kk] = *(const f16x8*)(ap + kk * 32);
    }
    float Cv[4];
#pragma unroll
    for (int r = 0; r < 4; ++r)
        Cv[r] = cvec[rowBase + wave * 16 + 4 * lg + r];

    int prow = rowBase + wave * 16 + (lane >> 2);
    int pw = (lane >> 1) & 1;

#pragma unroll 1
    for (int t = 0; t < 16; ++t) {
        int TT = (t + ph4) & 15;
        __syncthreads();
        {
            const char* hb = (const char*)h + (size_t)(c0 + TT * 64) * 512;
#pragma unroll
            for (int i = 0; i < 8; ++i) {
                int sb = i * 256 + wave * 64;
                int c = i * 8 + wave * 2 + (lane >> 5);
                gload_lds16(hb + (size_t)c * 512 + (((lane & 31) ^ (c & 31)) << 4),
                            hbuf + (size_t)sb * 16);
            }
        }
        // lane 4*wr+2*w(+1) loads word (row wr, word w of tile TT);
        // L2-resident, drains with the barrier
        u32 word = maskbits[(size_t)(split * 32 + TT * 2 + pw) * NN + prow];
        __syncthreads();

        f32x4 acc0 = {0.f, 0.f, 0.f, 0.f}, acc1 = {0.f, 0.f, 0.f, 0.f};
        f32x4 acc2 = {0.f, 0.f, 0.f, 0.f}, acc3 = {0.f, 0.f, 0.f, 0.f};
#pragma unroll
        for (int kk = 0; kk < 8; ++kk) {
            int ks = kk * 4 + lg;
            f16x8 b0 = *(const f16x8*)(hbuf + (size_t)l15 * 512
                                       + ((ks ^ l15) << 4));
            f16x8 b1 = *(const f16x8*)(hbuf + (size_t)(16 + l15) * 512
                                       + ((ks ^ (16 + l15)) << 4));
            f16x8 b2 = *(const f16x8*)(hbuf + (size_t)(32 + l15) * 512
                                       + ((ks ^ l15) << 4));
            f16x8 b3 = *(const f16x8*)(hbuf + (size_t)(48 + l15) * 512
                                       + ((ks ^ (16 + l15)) << 4));
            acc0 = __builtin_amdgcn_mfma_f32_16x16x32_f16(A[kk], b0, acc0, 0, 0, 0);
            acc1 = __builtin_amdgcn_mfma_f32_16x16x32_f16(A[kk], b1, acc1, 0, 0, 0);
            acc2 = __builtin_amdgcn_mfma_f32_16x16x32_f16(A[kk], b2, acc2, 0, 0, 0);
            acc3 = __builtin_amdgcn_mfma_f32_16x16x32_f16(A[kk], b3, acc3, 0, 0, 0);
        }

#pragma unroll
        for (int r = 0; r < 4; ++r) {
            int R = 4 * lg + r;
            u32 wA = (u32)__shfl((int)word, 4 * R, 64);
            u32 wB = (u32)__shfl((int)word, 4 * R + 2, 64);
            float v0 = ((wA >> l15) & 1u) ? acc0[r] : MASK_NEG;
            float v1 = ((wA >> (16 + l15)) & 1u) ? acc1[r] : MASK_NEG;
            float v2 = ((wB >> l15) & 1u) ? acc2[r] : MASK_NEG;
            float v3 = ((wB >> (16 + l15)) & 1u) ? acc3[r] : MASK_NEG;
            // masked: exp(-1e30 - C) underflows to exactly 0 (matches jax)
            size_t o = (size_t)(rowBase + wave * 16 + R) * NN + c0 + TT * 64 + l15;
            __builtin_nontemporal_store(__expf(v0 - Cv[r]), out + o);
            __builtin_nontemporal_store(__expf(v1 - Cv[r]), out + o + 16);
            __builtin_nontemporal_store(__expf(v2 - Cv[r]), out + o + 32);
            __builtin_nontemporal_store(__expf(v3 - Cv[r]), out + o + 48);
        }
    }
}

extern "C" void kernel_launch(void* const* d_in, const int* in_sizes, int n_in,
                              void* d_out, int out_size, void* d_ws, size_t ws_size,
                              hipStream_t stream) {
    const float* x   = (const float*)d_in[0];
    const int*   adj = (const int*)d_in[1];
    const float* w   = (const float*)d_in[2];
    float* out = (float*)d_out;
    char* ws = (char*)d_ws;

    // workspace layout (~13.2 MB, identical to r11/r13)
    f16* h    = (f16*)(ws);                                 // 4,194,304 B
    f16* wt   = (f16*)(ws + 4194304);                       //   131,072 B
    u32* mask = (u32*)(ws + 4194304 + 131072);              // 8,388,608 B
    float* pm = (float*)(ws + 4194304 + 131072 + 8388608);  // 8*NN f32
    float* ps = pm + 8 * NN;                                // 8*NN f32
    float* cv = ps + 8 * NN;                                // NN f32

    k0_wt<<<dim3(256), dim3(256), 0, stream>>>(w, wt);
    k1_h <<<dim3(256), dim3(256), 0, stream>>>(x, wt, h);
    k2a  <<<dim3(1024), dim3(256), 0, stream>>>(h, adj, mask, pm, ps);
    k2r  <<<dim3(32),  dim3(256), 0, stream>>>(pm, ps, cv);
    k2b  <<<dim3(1024), dim3(256), 0, stream>>>(h, mask, cv, out);
}